// Round 9
// baseline (154.462 us; speedup 1.0000x reference)
//
#include <hip/hip_runtime.h>

#define N_NODES 50000
#define N_EDGES 800000
#define DFEAT 96

// range partitioning: 4 ranges x 16384 nodes; 64 edge chunks of 12500
#define RBITS  14
#define RSIZE  16384
#define NRANGE 4
#define NCHUNK 64
#define CHUNK_E (N_EDGES / NCHUNK)   // 12500
#define HF_BLOCKS (NRANGE * NCHUNK)  // 256
#define NB 196                       // scan/reduce blocks of 256 nodes

typedef short bf16x8 __attribute__((ext_vector_type(8)));
typedef float f32x4  __attribute__((ext_vector_type(4)));

// ---- RNE fp32->bf16 packing ----
__device__ __forceinline__ unsigned bpack(float a, float b) {
    unsigned ua = __float_as_uint(a);
    unsigned ub = __float_as_uint(b);
    ua = (ua + 0x7FFFu + ((ua >> 16) & 1u)) >> 16;
    ub = (ub + 0x7FFFu + ((ub >> 16) & 1u)) >> 16;
    return ua | (ub << 16);
}
__device__ __forceinline__ unsigned short b1(float a) {
    unsigned u = __float_as_uint(a);
    u = (u + 0x7FFFu + ((u >> 16) & 1u)) >> 16;
    return (unsigned short)u;
}

// ---- pass 1: packed per-(range,chunk) LDS histogram (src low16, dst high16) ----
__global__ __launch_bounds__(512) void deg_hist_kernel(
    const int* __restrict__ src, const int* __restrict__ dst,
    unsigned* __restrict__ ptab) {
    __shared__ unsigned hh[RSIZE];   // 64 KB
    int tid = threadIdx.x;
    int r = blockIdx.x & (NRANGE - 1);
    int c = blockIdx.x >> 2;
    for (int i = tid; i < RSIZE; i += 512) hh[i] = 0;
    __syncthreads();
    int lo = r << RBITS;
    const int4* s4 = (const int4*)(src + c * CHUNK_E);
    const int4* d4 = (const int4*)(dst + c * CHUNK_E);
    for (int i = tid; i < CHUNK_E / 4; i += 512) {
        int4 s = s4[i];
        int4 d = d4[i];
        unsigned a;
        a = (unsigned)(s.x - lo); if (a < RSIZE) atomicAdd(&hh[a], 1u);
        a = (unsigned)(s.y - lo); if (a < RSIZE) atomicAdd(&hh[a], 1u);
        a = (unsigned)(s.z - lo); if (a < RSIZE) atomicAdd(&hh[a], 1u);
        a = (unsigned)(s.w - lo); if (a < RSIZE) atomicAdd(&hh[a], 1u);
        a = (unsigned)(d.x - lo); if (a < RSIZE) atomicAdd(&hh[a], 0x10000u);
        a = (unsigned)(d.y - lo); if (a < RSIZE) atomicAdd(&hh[a], 0x10000u);
        a = (unsigned)(d.z - lo); if (a < RSIZE) atomicAdd(&hh[a], 0x10000u);
        a = (unsigned)(d.w - lo); if (a < RSIZE) atomicAdd(&hh[a], 0x10000u);
    }
    __syncthreads();
    unsigned* pt = ptab + ((size_t)blockIdx.x << RBITS);   // bid = c*NRANGE + r
    for (int i = tid; i < RSIZE; i += 512) pt[i] = hh[i];
}

// ---- pass 2: reduce to degrees, write per-chunk u16 prefix, emit block sums ----
__global__ __launch_bounds__(256) void deg_reduce_kernel(
    const unsigned* __restrict__ ptab, unsigned short* __restrict__ pfx,
    int* __restrict__ deg_out, int* __restrict__ deg_in,
    int* __restrict__ bsum) {
    __shared__ int ws[4];
    int tid = threadIdx.x;
    int n = blockIdx.x * 256 + tid;
    int so = 0, si = 0;
    if (n < N_NODES) {
        int r = n >> RBITS, bin = n & (RSIZE - 1);
        #pragma unroll 8
        for (int c = 0; c < NCHUNK; ++c) {
            size_t idx = (((size_t)(c * NRANGE + r)) << RBITS) + bin;
            unsigned v = ptab[idx];
            so += (int)(v & 0xffffu);
            pfx[idx] = (unsigned short)si;   // prefix < chunk size 12500 << 65536
            si += (int)(v >> 16);
        }
        deg_out[n] = so;
        deg_in[n]  = si;
    }
    int v = si;
    #pragma unroll
    for (int off = 32; off; off >>= 1) v += __shfl_down(v, off, 64);
    if ((tid & 63) == 0) ws[tid >> 6] = v;
    __syncthreads();
    if (tid == 0) bsum[blockIdx.x] = ws[0] + ws[1] + ws[2] + ws[3];
}

// ---- pass 3: scan; each block recomputes its base from bsum ----
__global__ __launch_bounds__(256) void scan_final_kernel(
    const int* __restrict__ deg, const int* __restrict__ bsum,
    int* __restrict__ offs, int nb) {
    __shared__ int wsum[4];
    __shared__ int sbase;
    int tid = threadIdx.x, lane = tid & 63, wave = tid >> 6;
    int i = blockIdx.x * 256 + tid;
    int v = (i < N_NODES) ? deg[i] : 0;
    int x = v;
    #pragma unroll
    for (int off = 1; off < 64; off <<= 1) {
        int t = __shfl_up(x, off, 64);
        if (lane >= off) x += t;
    }
    if (lane == 63) wsum[wave] = x;
    if (wave == 0) {
        int s = 0;
        for (int j = lane; j < blockIdx.x; j += 64) s += bsum[j];
        #pragma unroll
        for (int off = 32; off; off >>= 1) s += __shfl_down(s, off, 64);
        if (lane == 0) sbase = s;
    }
    if (blockIdx.x == gridDim.x - 1 && wave == 1) {
        int s = 0;
        for (int j = lane; j < nb; j += 64) s += bsum[j];
        #pragma unroll
        for (int off = 32; off; off >>= 1) s += __shfl_down(s, off, 64);
        if (lane == 0) offs[N_NODES] = s;
    }
    __syncthreads();
    int wb = sbase;
    for (int w = 0; w < wave; ++w) wb += wsum[w];
    if (i < N_NODES) offs[i] = wb + x - v;
}

// ---- pass 4: CSR fill via LDS cursors (no global atomics) ----
__global__ __launch_bounds__(512) void fill_kernel(
    const int* __restrict__ src, const int* __restrict__ dst,
    const int* __restrict__ offs, const unsigned short* __restrict__ pfx,
    int* __restrict__ csr_src) {
    __shared__ int cur[RSIZE];   // 64 KB
    int tid = threadIdx.x;
    int r = blockIdx.x & (NRANGE - 1);
    int c = blockIdx.x >> 2;
    int lo = r << RBITS;
    const unsigned short* pf = pfx + ((size_t)blockIdx.x << RBITS);
    for (int i = tid; i < RSIZE; i += 512) {
        int gi = lo + i;
        int o = (gi < N_NODES) ? offs[gi] : 0;
        cur[i] = o + (int)pf[i];
    }
    __syncthreads();
    const int4* s4 = (const int4*)(src + c * CHUNK_E);
    const int4* d4 = (const int4*)(dst + c * CHUNK_E);
    for (int i = tid; i < CHUNK_E / 4; i += 512) {
        int4 s = s4[i];
        int4 d = d4[i];
        unsigned a;
        a = (unsigned)(d.x - lo); if (a < RSIZE) csr_src[atomicAdd(&cur[a], 1)] = s.x;
        a = (unsigned)(d.y - lo); if (a < RSIZE) csr_src[atomicAdd(&cur[a], 1)] = s.y;
        a = (unsigned)(d.z - lo); if (a < RSIZE) csr_src[atomicAdd(&cur[a], 1)] = s.z;
        a = (unsigned)(d.w - lo); if (a < RSIZE) csr_src[atomicAdd(&cur[a], 1)] = s.w;
    }
}

// ---- pass 5: MFMA GEMM  h = bf16( (x @ W) * inv_sqrt(deg_out[row]) ) ----
#define GEMM_ROWS 64
#define TLD 104
__global__ __launch_bounds__(256) void gemm_kernel(
    const float* __restrict__ x, const float* __restrict__ W,
    const int* __restrict__ deg_out, unsigned short* __restrict__ h, int nrows) {
    __shared__ unsigned short WT[96 * TLD];         // 19.5 KB
    __shared__ unsigned short xA[GEMM_ROWS * TLD];  // 13 KB
    int tid = threadIdx.x;
    int r0 = blockIdx.x * GEMM_ROWS;

    for (int i = tid; i < 48 * 96; i += 256) {
        int k2 = i / 96, n = i - k2 * 96;
        float w0 = W[(size_t)(2 * k2) * 96 + n];
        float w1 = W[(size_t)(2 * k2 + 1) * 96 + n];
        *(unsigned*)&WT[n * TLD + 2 * k2] = bpack(w0, w1);
    }
    for (int i = tid; i < GEMM_ROWS * 48; i += 256) {
        int m = i / 48, k2 = i - m * 48;
        int row = r0 + m; if (row >= nrows) row = nrows - 1;
        float2 v = *(const float2*)&x[(size_t)row * 96 + 2 * k2];
        *(unsigned*)&xA[m * TLD + 2 * k2] = bpack(v.x, v.y);
    }
    __syncthreads();

    int lane = tid & 63, wave = tid >> 6;
    int m16 = lane & 15;
    int g = lane >> 4;
    int rbase = wave * 16;

    bf16x8 afrag[3];
    #pragma unroll
    for (int ks = 0; ks < 3; ++ks)
        afrag[ks] = *(const bf16x8*)&xA[(rbase + m16) * TLD + ks * 32 + g * 8];

    f32x4 acc[6];
    #pragma unroll
    for (int nt = 0; nt < 6; ++nt) {
        f32x4 c = {0.f, 0.f, 0.f, 0.f};
        #pragma unroll
        for (int ks = 0; ks < 3; ++ks) {
            bf16x8 bfrag = *(const bf16x8*)&WT[(nt * 16 + m16) * TLD + ks * 32 + g * 8];
            c = __builtin_amdgcn_mfma_f32_16x16x32_bf16(afrag[ks], bfrag, c, 0, 0, 0);
        }
        acc[nt] = c;
    }

    float s[4];
    #pragma unroll
    for (int r = 0; r < 4; ++r) {
        int row = r0 + rbase + g * 4 + r;
        int d = (row < nrows) ? deg_out[row] : 1;
        s[r] = (d > 0) ? rsqrtf((float)d) : 0.f;
    }
    #pragma unroll
    for (int nt = 0; nt < 6; ++nt) {
        #pragma unroll
        for (int r = 0; r < 4; ++r) {
            int row = r0 + rbase + g * 4 + r;
            if (row < nrows)
                h[(size_t)row * 96 + nt * 16 + m16] = b1(acc[nt][r] * s[r]);
        }
    }
}

// ---- pass 6: aggregate  out[n] = inv_sqrt_in[n] * sum h[src_e] + b ----
// 32 lanes/node: 8 edge-octs x 4 column-lanes; combine via shfl_xor 4,8,16.
__device__ __forceinline__ void upadd(float* a, uint4 q) {
    a[0] += __uint_as_float(q.x << 16);
    a[1] += __uint_as_float(q.x & 0xffff0000u);
    a[2] += __uint_as_float(q.y << 16);
    a[3] += __uint_as_float(q.y & 0xffff0000u);
    a[4] += __uint_as_float(q.z << 16);
    a[5] += __uint_as_float(q.z & 0xffff0000u);
    a[6] += __uint_as_float(q.w << 16);
    a[7] += __uint_as_float(q.w & 0xffff0000u);
}

#define AGG_NODES 8
#define IDX_CAP 1024
__global__ __launch_bounds__(256) void agg_kernel(
    const unsigned short* __restrict__ h, const int* __restrict__ csr_src,
    const int* __restrict__ offs, const float* __restrict__ b,
    float* __restrict__ out) {
    __shared__ int sh_idx[IDX_CAP];
    __shared__ int sh_off[AGG_NODES + 1];
    int tid = threadIdx.x;
    int n0 = blockIdx.x * AGG_NODES;     // N_NODES % 8 == 0 -> no tail
    if (tid <= AGG_NODES) sh_off[tid] = offs[n0 + tid];
    __syncthreads();
    int s0 = sh_off[0];
    int len = sh_off[AGG_NODES] - s0;
    bool lds_ok = (len <= IDX_CAP);
    if (lds_ok) {
        for (int i = tid; i < len; i += 256) sh_idx[i] = csr_src[s0 + i];
    }
    __syncthreads();

    int node = tid >> 5;         // 0..7
    int lane32 = tid & 31;
    int j = lane32 & 3;          // uint4 slots j, j+4, j+8 of the 12-uint4 row
    int oct = lane32 >> 2;       // edge octant 0..7
    int start = sh_off[node], end = sh_off[node + 1];
    float acc[24];
    #pragma unroll
    for (int i = 0; i < 24; ++i) acc[i] = 0.f;
    const uint4* hb = (const uint4*)h;   // row = 12 uint4 (192 B)

    int e = start + oct;
    for (; e + 8 < end; e += 16) {       // edges e and e+8 of this oct's stride-8 list
        int i0 = lds_ok ? sh_idx[e - s0] : csr_src[e];
        int i1 = lds_ok ? sh_idx[e + 8 - s0] : csr_src[e + 8];
        size_t b0 = (size_t)i0 * 12 + j;
        size_t b1 = (size_t)i1 * 12 + j;
        uint4 q0 = hb[b0], q1 = hb[b0 + 4], q2 = hb[b0 + 8];
        uint4 p0 = hb[b1], p1 = hb[b1 + 4], p2 = hb[b1 + 8];
        upadd(acc + 0, q0); upadd(acc + 8, q1); upadd(acc + 16, q2);
        upadd(acc + 0, p0); upadd(acc + 8, p1); upadd(acc + 16, p2);
    }
    if (e < end) {
        int i0 = lds_ok ? sh_idx[e - s0] : csr_src[e];
        size_t b0 = (size_t)i0 * 12 + j;
        uint4 q0 = hb[b0], q1 = hb[b0 + 4], q2 = hb[b0 + 8];
        upadd(acc + 0, q0); upadd(acc + 8, q1); upadd(acc + 16, q2);
    }
    // combine octs (lanes node*32 .. node*32+31; xor 4,8,16 stay in-group)
    #pragma unroll
    for (int i = 0; i < 24; ++i) {
        acc[i] += __shfl_xor(acc[i], 4, 64);
        acc[i] += __shfl_xor(acc[i], 8, 64);
        acc[i] += __shfl_xor(acc[i], 16, 64);
    }
    if (oct != 0) return;
    float inv = (end > start) ? rsqrtf((float)(end - start)) : 0.f;
    int n = n0 + node;
    #pragma unroll
    for (int g = 0; g < 3; ++g) {
        int slot = j + 4 * g;            // cols 8*slot .. 8*slot+7
        float4 bb0 = *(const float4*)(b + 8 * slot);
        float4 bb1 = *(const float4*)(b + 8 * slot + 4);
        float4 r0, r1;
        r0.x = acc[g * 8 + 0] * inv + bb0.x;
        r0.y = acc[g * 8 + 1] * inv + bb0.y;
        r0.z = acc[g * 8 + 2] * inv + bb0.z;
        r0.w = acc[g * 8 + 3] * inv + bb0.w;
        r1.x = acc[g * 8 + 4] * inv + bb1.x;
        r1.y = acc[g * 8 + 5] * inv + bb1.y;
        r1.z = acc[g * 8 + 6] * inv + bb1.z;
        r1.w = acc[g * 8 + 7] * inv + bb1.w;
        float4* o = (float4*)(out + (size_t)n * DFEAT + 8 * slot);
        o[0] = r0; o[1] = r1;
    }
}

extern "C" void kernel_launch(void* const* d_in, const int* in_sizes, int n_in,
                              void* d_out, int out_size, void* d_ws, size_t ws_size,
                              hipStream_t stream) {
    const float* x  = (const float*)d_in[0];
    const float* W  = (const float*)d_in[1];
    const float* b  = (const float*)d_in[2];
    const int*   src = (const int*)d_in[3];
    const int*   dst = (const int*)d_in[4];
    float* out = (float*)d_out;

    // workspace layout
    int* deg_out = (int*)d_ws;                   // 50000
    int* deg_in  = deg_out + N_NODES;            // 50000
    int* offs    = deg_in + N_NODES;             // 50001
    int* csr_src = offs + N_NODES + 1;           // 800000
    int* bsum    = csr_src + N_EDGES;            // 256
    size_t off1 = (((size_t)(3 * N_NODES + 1 + N_EDGES + 256)) * 4 + 255) & ~(size_t)255;
    unsigned* ptab = (unsigned*)((char*)d_ws + off1);            // 256*16384 u32 (16.8 MB)
    size_t off2 = off1 + ((size_t)HF_BLOCKS << RBITS) * 4;
    unsigned short* pfx = (unsigned short*)((char*)d_ws + off2); // 256*16384 u16 (8.4 MB)
    size_t off3 = (off2 + ((size_t)HF_BLOCKS << RBITS) * 2 + 255) & ~(size_t)255;
    unsigned short* h = (unsigned short*)((char*)d_ws + off3);   // 50000*96 bf16 (9.6 MB)

    deg_hist_kernel<<<HF_BLOCKS, 512, 0, stream>>>(src, dst, ptab);
    deg_reduce_kernel<<<NB, 256, 0, stream>>>(ptab, pfx, deg_out, deg_in, bsum);
    scan_final_kernel<<<NB, 256, 0, stream>>>(deg_in, bsum, offs, NB);
    fill_kernel<<<HF_BLOCKS, 512, 0, stream>>>(src, dst, offs, pfx, csr_src);
    gemm_kernel<<<(N_NODES + GEMM_ROWS - 1) / GEMM_ROWS, 256, 0, stream>>>(
        x, W, deg_out, h, N_NODES);
    agg_kernel<<<N_NODES / AGG_NODES, 256, 0, stream>>>(h, csr_src, offs, b, out);
}

// Round 10
// 145.229 us; speedup vs baseline: 1.0636x; 1.0636x over previous
//
#include <hip/hip_runtime.h>

#define N_NODES 50000
#define N_EDGES 800000
#define DFEAT 96

// range partitioning: 4 ranges x 16384 nodes; 64 edge chunks of 12500
#define RBITS  14
#define RSIZE  16384
#define NRANGE 4
#define NCHUNK 64
#define CHUNK_E (N_EDGES / NCHUNK)   // 12500
#define HF_BLOCKS (NRANGE * NCHUNK)  // 256
#define NB 196                       // scan/reduce blocks of 256 nodes

typedef short bf16x8 __attribute__((ext_vector_type(8)));
typedef float f32x4  __attribute__((ext_vector_type(4)));

// ---- RNE fp32->bf16 packing ----
__device__ __forceinline__ unsigned bpack(float a, float b) {
    unsigned ua = __float_as_uint(a);
    unsigned ub = __float_as_uint(b);
    ua = (ua + 0x7FFFu + ((ua >> 16) & 1u)) >> 16;
    ub = (ub + 0x7FFFu + ((ub >> 16) & 1u)) >> 16;
    return ua | (ub << 16);
}
__device__ __forceinline__ unsigned short b1(float a) {
    unsigned u = __float_as_uint(a);
    u = (u + 0x7FFFu + ((u >> 16) & 1u)) >> 16;
    return (unsigned short)u;
}

// ---- pass 1: packed per-(range,chunk) LDS histogram (src low16, dst high16) ----
__global__ __launch_bounds__(512) void deg_hist_kernel(
    const int* __restrict__ src, const int* __restrict__ dst,
    unsigned* __restrict__ ptab) {
    __shared__ unsigned hh[RSIZE];   // 64 KB
    int tid = threadIdx.x;
    int r = blockIdx.x & (NRANGE - 1);
    int c = blockIdx.x >> 2;
    for (int i = tid; i < RSIZE; i += 512) hh[i] = 0;
    __syncthreads();
    int lo = r << RBITS;
    const int4* s4 = (const int4*)(src + c * CHUNK_E);
    const int4* d4 = (const int4*)(dst + c * CHUNK_E);
    for (int i = tid; i < CHUNK_E / 4; i += 512) {
        int4 s = s4[i];
        int4 d = d4[i];
        unsigned a;
        a = (unsigned)(s.x - lo); if (a < RSIZE) atomicAdd(&hh[a], 1u);
        a = (unsigned)(s.y - lo); if (a < RSIZE) atomicAdd(&hh[a], 1u);
        a = (unsigned)(s.z - lo); if (a < RSIZE) atomicAdd(&hh[a], 1u);
        a = (unsigned)(s.w - lo); if (a < RSIZE) atomicAdd(&hh[a], 1u);
        a = (unsigned)(d.x - lo); if (a < RSIZE) atomicAdd(&hh[a], 0x10000u);
        a = (unsigned)(d.y - lo); if (a < RSIZE) atomicAdd(&hh[a], 0x10000u);
        a = (unsigned)(d.z - lo); if (a < RSIZE) atomicAdd(&hh[a], 0x10000u);
        a = (unsigned)(d.w - lo); if (a < RSIZE) atomicAdd(&hh[a], 0x10000u);
    }
    __syncthreads();
    unsigned* pt = ptab + ((size_t)blockIdx.x << RBITS);   // bid = c*NRANGE + r
    for (int i = tid; i < RSIZE; i += 512) pt[i] = hh[i];
}

// ---- pass 2: reduce to degrees, write per-chunk u16 prefix, emit block sums ----
__global__ __launch_bounds__(256) void deg_reduce_kernel(
    const unsigned* __restrict__ ptab, unsigned short* __restrict__ pfx,
    int* __restrict__ deg_out, int* __restrict__ deg_in,
    int* __restrict__ bsum) {
    __shared__ int ws[4];
    int tid = threadIdx.x;
    int n = blockIdx.x * 256 + tid;
    int so = 0, si = 0;
    if (n < N_NODES) {
        int r = n >> RBITS, bin = n & (RSIZE - 1);
        #pragma unroll 8
        for (int c = 0; c < NCHUNK; ++c) {
            size_t idx = (((size_t)(c * NRANGE + r)) << RBITS) + bin;
            unsigned v = ptab[idx];
            so += (int)(v & 0xffffu);
            pfx[idx] = (unsigned short)si;   // prefix < chunk size 12500 << 65536
            si += (int)(v >> 16);
        }
        deg_out[n] = so;
        deg_in[n]  = si;
    }
    int v = si;
    #pragma unroll
    for (int off = 32; off; off >>= 1) v += __shfl_down(v, off, 64);
    if ((tid & 63) == 0) ws[tid >> 6] = v;
    __syncthreads();
    if (tid == 0) bsum[blockIdx.x] = ws[0] + ws[1] + ws[2] + ws[3];
}

// ---- pass 3: scan; each block recomputes its base from bsum ----
__global__ __launch_bounds__(256) void scan_final_kernel(
    const int* __restrict__ deg, const int* __restrict__ bsum,
    int* __restrict__ offs, int nb) {
    __shared__ int wsum[4];
    __shared__ int sbase;
    int tid = threadIdx.x, lane = tid & 63, wave = tid >> 6;
    int i = blockIdx.x * 256 + tid;
    int v = (i < N_NODES) ? deg[i] : 0;
    int x = v;
    #pragma unroll
    for (int off = 1; off < 64; off <<= 1) {
        int t = __shfl_up(x, off, 64);
        if (lane >= off) x += t;
    }
    if (lane == 63) wsum[wave] = x;
    if (wave == 0) {
        int s = 0;
        for (int j = lane; j < blockIdx.x; j += 64) s += bsum[j];
        #pragma unroll
        for (int off = 32; off; off >>= 1) s += __shfl_down(s, off, 64);
        if (lane == 0) sbase = s;
    }
    if (blockIdx.x == gridDim.x - 1 && wave == 1) {
        int s = 0;
        for (int j = lane; j < nb; j += 64) s += bsum[j];
        #pragma unroll
        for (int off = 32; off; off >>= 1) s += __shfl_down(s, off, 64);
        if (lane == 0) offs[N_NODES] = s;
    }
    __syncthreads();
    int wb = sbase;
    for (int w = 0; w < wave; ++w) wb += wsum[w];
    if (i < N_NODES) offs[i] = wb + x - v;
}

// ---- pass 4: CSR fill via LDS cursors (no global atomics) ----
__global__ __launch_bounds__(512) void fill_kernel(
    const int* __restrict__ src, const int* __restrict__ dst,
    const int* __restrict__ offs, const unsigned short* __restrict__ pfx,
    int* __restrict__ csr_src) {
    __shared__ int cur[RSIZE];   // 64 KB
    int tid = threadIdx.x;
    int r = blockIdx.x & (NRANGE - 1);
    int c = blockIdx.x >> 2;
    int lo = r << RBITS;
    const unsigned short* pf = pfx + ((size_t)blockIdx.x << RBITS);
    for (int i = tid; i < RSIZE; i += 512) {
        int gi = lo + i;
        int o = (gi < N_NODES) ? offs[gi] : 0;
        cur[i] = o + (int)pf[i];
    }
    __syncthreads();
    const int4* s4 = (const int4*)(src + c * CHUNK_E);
    const int4* d4 = (const int4*)(dst + c * CHUNK_E);
    for (int i = tid; i < CHUNK_E / 4; i += 512) {
        int4 s = s4[i];
        int4 d = d4[i];
        unsigned a;
        a = (unsigned)(d.x - lo); if (a < RSIZE) csr_src[atomicAdd(&cur[a], 1)] = s.x;
        a = (unsigned)(d.y - lo); if (a < RSIZE) csr_src[atomicAdd(&cur[a], 1)] = s.y;
        a = (unsigned)(d.z - lo); if (a < RSIZE) csr_src[atomicAdd(&cur[a], 1)] = s.z;
        a = (unsigned)(d.w - lo); if (a < RSIZE) csr_src[atomicAdd(&cur[a], 1)] = s.w;
    }
}

// ---- pass 5: MFMA GEMM  h = bf16( (x @ W) * inv_sqrt(deg_out[row]) ) ----
#define GEMM_ROWS 64
#define TLD 104
__global__ __launch_bounds__(256) void gemm_kernel(
    const float* __restrict__ x, const float* __restrict__ W,
    const int* __restrict__ deg_out, unsigned short* __restrict__ h, int nrows) {
    __shared__ unsigned short WT[96 * TLD];         // 19.5 KB
    __shared__ unsigned short xA[GEMM_ROWS * TLD];  // 13 KB
    int tid = threadIdx.x;
    int r0 = blockIdx.x * GEMM_ROWS;

    for (int i = tid; i < 48 * 96; i += 256) {
        int k2 = i / 96, n = i - k2 * 96;
        float w0 = W[(size_t)(2 * k2) * 96 + n];
        float w1 = W[(size_t)(2 * k2 + 1) * 96 + n];
        *(unsigned*)&WT[n * TLD + 2 * k2] = bpack(w0, w1);
    }
    for (int i = tid; i < GEMM_ROWS * 48; i += 256) {
        int m = i / 48, k2 = i - m * 48;
        int row = r0 + m; if (row >= nrows) row = nrows - 1;
        float2 v = *(const float2*)&x[(size_t)row * 96 + 2 * k2];
        *(unsigned*)&xA[m * TLD + 2 * k2] = bpack(v.x, v.y);
    }
    __syncthreads();

    int lane = tid & 63, wave = tid >> 6;
    int m16 = lane & 15;
    int g = lane >> 4;
    int rbase = wave * 16;

    bf16x8 afrag[3];
    #pragma unroll
    for (int ks = 0; ks < 3; ++ks)
        afrag[ks] = *(const bf16x8*)&xA[(rbase + m16) * TLD + ks * 32 + g * 8];

    f32x4 acc[6];
    #pragma unroll
    for (int nt = 0; nt < 6; ++nt) {
        f32x4 c = {0.f, 0.f, 0.f, 0.f};
        #pragma unroll
        for (int ks = 0; ks < 3; ++ks) {
            bf16x8 bfrag = *(const bf16x8*)&WT[(nt * 16 + m16) * TLD + ks * 32 + g * 8];
            c = __builtin_amdgcn_mfma_f32_16x16x32_bf16(afrag[ks], bfrag, c, 0, 0, 0);
        }
        acc[nt] = c;
    }

    float s[4];
    #pragma unroll
    for (int r = 0; r < 4; ++r) {
        int row = r0 + rbase + g * 4 + r;
        int d = (row < nrows) ? deg_out[row] : 1;
        s[r] = (d > 0) ? rsqrtf((float)d) : 0.f;
    }
    #pragma unroll
    for (int nt = 0; nt < 6; ++nt) {
        #pragma unroll
        for (int r = 0; r < 4; ++r) {
            int row = r0 + rbase + g * 4 + r;
            if (row < nrows)
                h[(size_t)row * 96 + nt * 16 + m16] = b1(acc[nt][r] * s[r]);
        }
    }
}

// ---- pass 6: aggregate  out[n] = inv_sqrt_in[n] * sum h[src_e] + b ----
// 16 lanes/node (4 edge-quarters x 4 col-lanes), csr segment staged in LDS.
// [r9 post-mortem: 32 lanes/node regressed — agg is fabric-BW-bound; 16 is best]
__device__ __forceinline__ void upadd(float* a, uint4 q) {
    a[0] += __uint_as_float(q.x << 16);
    a[1] += __uint_as_float(q.x & 0xffff0000u);
    a[2] += __uint_as_float(q.y << 16);
    a[3] += __uint_as_float(q.y & 0xffff0000u);
    a[4] += __uint_as_float(q.z << 16);
    a[5] += __uint_as_float(q.z & 0xffff0000u);
    a[6] += __uint_as_float(q.w << 16);
    a[7] += __uint_as_float(q.w & 0xffff0000u);
}

#define AGG_NODES 16
#define IDX_CAP 2048
__global__ __launch_bounds__(256) void agg_kernel(
    const unsigned short* __restrict__ h, const int* __restrict__ csr_src,
    const int* __restrict__ offs, const float* __restrict__ b,
    float* __restrict__ out) {
    __shared__ int sh_idx[IDX_CAP];
    __shared__ int sh_off[AGG_NODES + 1];
    int tid = threadIdx.x;
    int n0 = blockIdx.x * AGG_NODES;
    if (tid <= AGG_NODES) sh_off[tid] = offs[n0 + tid];
    __syncthreads();
    int s0 = sh_off[0];
    int len = sh_off[AGG_NODES] - s0;
    bool lds_ok = (len <= IDX_CAP);
    if (lds_ok) {
        for (int i = tid; i < len; i += 256) sh_idx[i] = csr_src[s0 + i];
    }
    __syncthreads();

    int node = tid >> 4;
    int lane16 = tid & 15;
    int j = lane16 & 3;          // uint4 slots j, j+4, j+8 of the 12-uint4 row
    int q = lane16 >> 2;         // edge quarter 0..3
    int start = sh_off[node], end = sh_off[node + 1];
    float acc[24];
    #pragma unroll
    for (int i = 0; i < 24; ++i) acc[i] = 0.f;
    const uint4* hb = (const uint4*)h;   // row = 12 uint4 (192 B)

    int e = start + q;
    for (; e + 4 < end; e += 8) {
        int i0 = lds_ok ? sh_idx[e - s0] : csr_src[e];
        int i1 = lds_ok ? sh_idx[e + 4 - s0] : csr_src[e + 4];
        size_t b0 = (size_t)i0 * 12 + j;
        size_t b1 = (size_t)i1 * 12 + j;
        uint4 q0 = hb[b0], q1 = hb[b0 + 4], q2 = hb[b0 + 8];
        uint4 p0 = hb[b1], p1 = hb[b1 + 4], p2 = hb[b1 + 8];
        upadd(acc + 0, q0); upadd(acc + 8, q1); upadd(acc + 16, q2);
        upadd(acc + 0, p0); upadd(acc + 8, p1); upadd(acc + 16, p2);
    }
    if (e < end) {
        int i0 = lds_ok ? sh_idx[e - s0] : csr_src[e];
        size_t b0 = (size_t)i0 * 12 + j;
        uint4 q0 = hb[b0], q1 = hb[b0 + 4], q2 = hb[b0 + 8];
        upadd(acc + 0, q0); upadd(acc + 8, q1); upadd(acc + 16, q2);
    }
    #pragma unroll
    for (int i = 0; i < 24; ++i) {
        acc[i] += __shfl_xor(acc[i], 4, 64);
        acc[i] += __shfl_xor(acc[i], 8, 64);
    }
    if (q != 0) return;
    float inv = (end > start) ? rsqrtf((float)(end - start)) : 0.f;
    int n = n0 + node;
    #pragma unroll
    for (int g = 0; g < 3; ++g) {
        int slot = j + 4 * g;
        float4 bb0 = *(const float4*)(b + 8 * slot);
        float4 bb1 = *(const float4*)(b + 8 * slot + 4);
        float4 r0, r1;
        r0.x = acc[g * 8 + 0] * inv + bb0.x;
        r0.y = acc[g * 8 + 1] * inv + bb0.y;
        r0.z = acc[g * 8 + 2] * inv + bb0.z;
        r0.w = acc[g * 8 + 3] * inv + bb0.w;
        r1.x = acc[g * 8 + 4] * inv + bb1.x;
        r1.y = acc[g * 8 + 5] * inv + bb1.y;
        r1.z = acc[g * 8 + 6] * inv + bb1.z;
        r1.w = acc[g * 8 + 7] * inv + bb1.w;
        float4* o = (float4*)(out + (size_t)n * DFEAT + 8 * slot);
        o[0] = r0; o[1] = r1;
    }
}

extern "C" void kernel_launch(void* const* d_in, const int* in_sizes, int n_in,
                              void* d_out, int out_size, void* d_ws, size_t ws_size,
                              hipStream_t stream) {
    const float* x  = (const float*)d_in[0];
    const float* W  = (const float*)d_in[1];
    const float* b  = (const float*)d_in[2];
    const int*   src = (const int*)d_in[3];
    const int*   dst = (const int*)d_in[4];
    float* out = (float*)d_out;

    // workspace layout
    int* deg_out = (int*)d_ws;                   // 50000
    int* deg_in  = deg_out + N_NODES;            // 50000
    int* offs    = deg_in + N_NODES;             // 50001
    int* csr_src = offs + N_NODES + 1;           // 800000
    int* bsum    = csr_src + N_EDGES;            // 256
    size_t off1 = (((size_t)(3 * N_NODES + 1 + N_EDGES + 256)) * 4 + 255) & ~(size_t)255;
    unsigned* ptab = (unsigned*)((char*)d_ws + off1);            // 256*16384 u32 (16.8 MB)
    size_t off2 = off1 + ((size_t)HF_BLOCKS << RBITS) * 4;
    unsigned short* pfx = (unsigned short*)((char*)d_ws + off2); // 256*16384 u16 (8.4 MB)
    size_t off3 = (off2 + ((size_t)HF_BLOCKS << RBITS) * 2 + 255) & ~(size_t)255;
    unsigned short* h = (unsigned short*)((char*)d_ws + off3);   // 50000*96 bf16 (9.6 MB)

    deg_hist_kernel<<<HF_BLOCKS, 512, 0, stream>>>(src, dst, ptab);
    deg_reduce_kernel<<<NB, 256, 0, stream>>>(ptab, pfx, deg_out, deg_in, bsum);
    scan_final_kernel<<<NB, 256, 0, stream>>>(deg_in, bsum, offs, NB);
    fill_kernel<<<HF_BLOCKS, 512, 0, stream>>>(src, dst, offs, pfx, csr_src);
    gemm_kernel<<<(N_NODES + GEMM_ROWS - 1) / GEMM_ROWS, 256, 0, stream>>>(
        x, W, deg_out, h, N_NODES);
    agg_kernel<<<N_NODES / AGG_NODES, 256, 0, stream>>>(h, csr_src, offs, b, out);
}